// Round 1
// baseline (181.146 us; speedup 1.0000x reference)
//
#include <hip/hip_runtime.h>
#include <hip/hip_bf16.h>
#include <math.h>

// Problem constants (fixed by the reference)
#define BB   8
#define NQ   256
#define NKV  1024
#define DD   256   // DQ == DK == DV == 256
#define HH   128   // hidden

typedef float f16v __attribute__((ext_vector_type(16)));

// ---------------------------------------------------------------------------
// Kernel 1: fused projection + exp.
//   Eq[row][h] = exp(2 * dot(Q[row,:], Wq[h,:]))   rows 0..2047   (b*NQ+q)
//   Ek[row][h] = exp(2 * dot(K[row,:], Wk[h,:]))   rows 0..8191   (b*NKV+k)
// 16-row x 128-h tile per block, 128 threads, d chunked by 32.
// Thread computes a 4-row x 4-h register tile (float4 accs) from LDS.
// ---------------------------------------------------------------------------
__global__ __launch_bounds__(128) void proj_exp_kernel(
    const float* __restrict__ Q, const float* __restrict__ K,
    const float* __restrict__ Wq, const float* __restrict__ Wk,
    float* __restrict__ eqb, float* __restrict__ ekb)
{
    __shared__ __align__(16) float At[32][20];   // [d][row] transposed A tile
    __shared__ __align__(16) float Wt[32][132];  // [d][h]  transposed W tile

    const int bid = blockIdx.x;
    const bool isQ = bid < (BB * NQ / 16);          // first 128 blocks: Q part
    const float* A = isQ ? Q : K;
    const float* W = isQ ? Wq : Wk;
    float* Out     = isQ ? eqb : ekb;
    const int arow0 = (isQ ? bid : bid - (BB * NQ / 16)) * 16;

    const int tid  = threadIdx.x;
    const int rc   = tid >> 5;   // 0..3  -> rows rc*4..rc*4+3
    const int hc   = tid & 31;   // 0..31 -> h = hc*4..hc*4+3
    const int r_st = tid >> 3;   // 0..15 staging row
    const int dq   = tid & 7;    // 0..7  staging d-quad

    float4 c0 = {0.f,0.f,0.f,0.f}, c1 = c0, c2 = c0, c3 = c0;

    for (int dc = 0; dc < DD; dc += 32) {
        // issue global loads before the barrier (overlap with prior compute)
        float4 a4 = *(const float4*)(A + (size_t)(arow0 + r_st) * DD + dc + dq * 4);
        float4 w4[8];
#pragma unroll
        for (int t = 0; t < 8; ++t) {
            int idx = tid + t * 128;
            int h = idx >> 3, dw = idx & 7;
            w4[t] = *(const float4*)(W + (size_t)h * DD + dc + dw * 4);
        }
        __syncthreads();   // previous iteration's LDS reads complete
        At[dq*4+0][r_st] = a4.x;
        At[dq*4+1][r_st] = a4.y;
        At[dq*4+2][r_st] = a4.z;
        At[dq*4+3][r_st] = a4.w;
#pragma unroll
        for (int t = 0; t < 8; ++t) {
            int idx = tid + t * 128;
            int h = idx >> 3, dw = idx & 7;
            Wt[dw*4+0][h] = w4[t].x;
            Wt[dw*4+1][h] = w4[t].y;
            Wt[dw*4+2][h] = w4[t].z;
            Wt[dw*4+3][h] = w4[t].w;
        }
        __syncthreads();
#pragma unroll
        for (int d = 0; d < 32; ++d) {
            float4 av = *(const float4*)&At[d][rc * 4];
            float4 wv = *(const float4*)&Wt[d][hc * 4];
            c0.x = fmaf(av.x, wv.x, c0.x); c0.y = fmaf(av.x, wv.y, c0.y);
            c0.z = fmaf(av.x, wv.z, c0.z); c0.w = fmaf(av.x, wv.w, c0.w);
            c1.x = fmaf(av.y, wv.x, c1.x); c1.y = fmaf(av.y, wv.y, c1.y);
            c1.z = fmaf(av.y, wv.z, c1.z); c1.w = fmaf(av.y, wv.w, c1.w);
            c2.x = fmaf(av.z, wv.x, c2.x); c2.y = fmaf(av.z, wv.y, c2.y);
            c2.z = fmaf(av.z, wv.z, c2.z); c2.w = fmaf(av.z, wv.w, c2.w);
            c3.x = fmaf(av.w, wv.x, c3.x); c3.y = fmaf(av.w, wv.y, c3.y);
            c3.z = fmaf(av.w, wv.z, c3.z); c3.w = fmaf(av.w, wv.w, c3.w);
        }
    }

    // epilogue: exp(2x), coalesced float4 store
    {
        float4 o;
        float* p;
        p = Out + (size_t)(arow0 + rc*4 + 0) * HH + hc * 4;
        o.x = __expf(2.f*c0.x); o.y = __expf(2.f*c0.y); o.z = __expf(2.f*c0.z); o.w = __expf(2.f*c0.w);
        *(float4*)p = o;
        p = Out + (size_t)(arow0 + rc*4 + 1) * HH + hc * 4;
        o.x = __expf(2.f*c1.x); o.y = __expf(2.f*c1.y); o.z = __expf(2.f*c1.z); o.w = __expf(2.f*c1.w);
        *(float4*)p = o;
        p = Out + (size_t)(arow0 + rc*4 + 2) * HH + hc * 4;
        o.x = __expf(2.f*c2.x); o.y = __expf(2.f*c2.y); o.z = __expf(2.f*c2.z); o.w = __expf(2.f*c2.w);
        *(float4*)p = o;
        p = Out + (size_t)(arow0 + rc*4 + 3) * HH + hc * 4;
        o.x = __expf(2.f*c3.x); o.y = __expf(2.f*c3.y); o.z = __expf(2.f*c3.z); o.w = __expf(2.f*c3.w);
        *(float4*)p = o;
    }
}

// ---------------------------------------------------------------------------
// Kernel 2: fused scores + masked softmax + PV.
// Grid: 256 blocks (b = bid/32, q-tile of 8 rows), 512 threads (8 waves).
// Score phase: thread = (ks, qg, hg): 4 q-rows x 16 h in registers; Ek
//   streamed from L2 (2-deep register double-buffer); per term:
//   score += Wv[h]*tanh(q+k) = Wv[h] - 2*Wv[h]*rcp(1 + Eq*Ek).
//   8-lane shfl_xor reduces h-groups; k-steps with k0 >= valid_len skipped.
// Softmax: one wave per q-row, masked, P written back to LDS.
// PV phase: one wave per q-row, lane owns 4 v-columns, full-row coalesced V.
// ---------------------------------------------------------------------------
__global__ __launch_bounds__(512) void attn_kernel(
    const float* __restrict__ V, const int* __restrict__ vls,
    const float* __restrict__ Wv,
    const float* __restrict__ eqb, const float* __restrict__ ekb,
    float* __restrict__ out)
{
    __shared__ float sc[8][1024];   // scores then P
    __shared__ float rsum[8];

    const int tid  = threadIdx.x;
    const int bid  = blockIdx.x;
    const int b    = bid >> 5;
    const int q0   = (bid & 31) << 3;
    const int w    = tid >> 6;          // wave 0..7
    const int lane = tid & 63;
    const int qg   = w & 1;             // q-group (rows qg*4..qg*4+3)
    const int ks   = ((w >> 1) << 3) + (lane >> 3);  // 0..31 k-slot
    const int hg   = lane & 7;          // h-group (h = hg*16..hg*16+15)
    const int vl   = vls[b];

    // Wv slice: nw2[j] = -2*Wv[hg*16+j]; swv = sum of own Wv (acc init)
    f16v nw2;
    float swv = 0.f;
#pragma unroll
    for (int i = 0; i < 4; ++i) {
        float4 v4 = *(const float4*)(Wv + hg * 16 + i * 4);
        nw2[i*4+0] = -2.f * v4.x; nw2[i*4+1] = -2.f * v4.y;
        nw2[i*4+2] = -2.f * v4.z; nw2[i*4+3] = -2.f * v4.w;
        swv += v4.x + v4.y + v4.z + v4.w;
    }

    // Eq rows in registers: 4 rows x 16 h
    f16v eq0, eq1, eq2, eq3;
    {
        const float4* p;
        float4 x0, x1, x2, x3;
        p = (const float4*)(eqb + (size_t)(b*NQ + q0 + qg*4 + 0) * HH + hg * 16);
        x0=p[0]; x1=p[1]; x2=p[2]; x3=p[3];
        eq0[0]=x0.x;eq0[1]=x0.y;eq0[2]=x0.z;eq0[3]=x0.w; eq0[4]=x1.x;eq0[5]=x1.y;eq0[6]=x1.z;eq0[7]=x1.w;
        eq0[8]=x2.x;eq0[9]=x2.y;eq0[10]=x2.z;eq0[11]=x2.w; eq0[12]=x3.x;eq0[13]=x3.y;eq0[14]=x3.z;eq0[15]=x3.w;
        p = (const float4*)(eqb + (size_t)(b*NQ + q0 + qg*4 + 1) * HH + hg * 16);
        x0=p[0]; x1=p[1]; x2=p[2]; x3=p[3];
        eq1[0]=x0.x;eq1[1]=x0.y;eq1[2]=x0.z;eq1[3]=x0.w; eq1[4]=x1.x;eq1[5]=x1.y;eq1[6]=x1.z;eq1[7]=x1.w;
        eq1[8]=x2.x;eq1[9]=x2.y;eq1[10]=x2.z;eq1[11]=x2.w; eq1[12]=x3.x;eq1[13]=x3.y;eq1[14]=x3.z;eq1[15]=x3.w;
        p = (const float4*)(eqb + (size_t)(b*NQ + q0 + qg*4 + 2) * HH + hg * 16);
        x0=p[0]; x1=p[1]; x2=p[2]; x3=p[3];
        eq2[0]=x0.x;eq2[1]=x0.y;eq2[2]=x0.z;eq2[3]=x0.w; eq2[4]=x1.x;eq2[5]=x1.y;eq2[6]=x1.z;eq2[7]=x1.w;
        eq2[8]=x2.x;eq2[9]=x2.y;eq2[10]=x2.z;eq2[11]=x2.w; eq2[12]=x3.x;eq2[13]=x3.y;eq2[14]=x3.z;eq2[15]=x3.w;
        p = (const float4*)(eqb + (size_t)(b*NQ + q0 + qg*4 + 3) * HH + hg * 16);
        x0=p[0]; x1=p[1]; x2=p[2]; x3=p[3];
        eq3[0]=x0.x;eq3[1]=x0.y;eq3[2]=x0.z;eq3[3]=x0.w; eq3[4]=x1.x;eq3[5]=x1.y;eq3[6]=x1.z;eq3[7]=x1.w;
        eq3[8]=x2.x;eq3[9]=x2.y;eq3[10]=x2.z;eq3[11]=x2.w; eq3[12]=x3.x;eq3[13]=x3.y;eq3[14]=x3.z;eq3[15]=x3.w;
    }

    const float* ekbase = ekb + (size_t)(b * NKV) * HH + hg * 16;

    auto loadEk = [&](f16v& e, int step) {
        const float4* p = (const float4*)(ekbase + (size_t)(step * 32 + ks) * HH);
        float4 x0 = p[0], x1 = p[1], x2 = p[2], x3 = p[3];
        e[0]=x0.x;e[1]=x0.y;e[2]=x0.z;e[3]=x0.w; e[4]=x1.x;e[5]=x1.y;e[6]=x1.z;e[7]=x1.w;
        e[8]=x2.x;e[9]=x2.y;e[10]=x2.z;e[11]=x2.w; e[12]=x3.x;e[13]=x3.y;e[14]=x3.z;e[15]=x3.w;
    };

    auto body = [&](const f16v& e, int step) {
        float a0 = swv, a1 = swv, a2 = swv, a3 = swv;
#pragma unroll
        for (int j = 0; j < 16; ++j) {
            float ej = e[j];
            float t0 = fmaf(eq0[j], ej, 1.0f);
            float t1 = fmaf(eq1[j], ej, 1.0f);
            float t2 = fmaf(eq2[j], ej, 1.0f);
            float t3 = fmaf(eq3[j], ej, 1.0f);
            float r0 = __builtin_amdgcn_rcpf(t0);
            float r1 = __builtin_amdgcn_rcpf(t1);
            float r2 = __builtin_amdgcn_rcpf(t2);
            float r3 = __builtin_amdgcn_rcpf(t3);
            float nj = nw2[j];
            a0 = fmaf(nj, r0, a0);
            a1 = fmaf(nj, r1, a1);
            a2 = fmaf(nj, r2, a2);
            a3 = fmaf(nj, r3, a3);
        }
        // reduce the 8 h-groups (lanes hg 0..7)
        a0 += __shfl_xor(a0, 1); a0 += __shfl_xor(a0, 2); a0 += __shfl_xor(a0, 4);
        a1 += __shfl_xor(a1, 1); a1 += __shfl_xor(a1, 2); a1 += __shfl_xor(a1, 4);
        a2 += __shfl_xor(a2, 1); a2 += __shfl_xor(a2, 2); a2 += __shfl_xor(a2, 4);
        a3 += __shfl_xor(a3, 1); a3 += __shfl_xor(a3, 2); a3 += __shfl_xor(a3, 4);
        if (hg == 0) {
            int kk = step * 32 + ks;
            sc[qg*4+0][kk] = a0;
            sc[qg*4+1][kk] = a1;
            sc[qg*4+2][kk] = a2;
            sc[qg*4+3][kk] = a3;
        }
    };

    // ---- score phase: only k-steps below valid_len (mask makes rest moot)
    const int nsteps = (vl + 31) >> 5;   // <= 32
    f16v ekA, ekB;
    loadEk(ekA, 0);
    for (int t = 0; t < nsteps; t += 2) {
        if (t + 1 < nsteps) loadEk(ekB, t + 1);
        body(ekA, t);
        if (t + 1 < nsteps) {
            if (t + 2 < nsteps) loadEk(ekA, t + 2);
            body(ekB, t + 1);
        }
    }
    __syncthreads();

    // ---- masked softmax: wave w owns row q=w
    {
        const int q = w;
        float m = -1e30f;
        float sv[16];
#pragma unroll
        for (int i = 0; i < 16; ++i) {
            int kk = i * 64 + lane;
            float s = sc[q][kk];
            sv[i] = s;
            if (kk < vl) m = fmaxf(m, s);
        }
#pragma unroll
        for (int off = 1; off < 64; off <<= 1) m = fmaxf(m, __shfl_xor(m, off));
        float sum = 0.f;
#pragma unroll
        for (int i = 0; i < 16; ++i) {
            int kk = i * 64 + lane;
            float p = (kk < vl) ? __expf(sv[i] - m) : 0.f;
            sum += p;
            sc[q][kk] = p;
        }
#pragma unroll
        for (int off = 1; off < 64; off <<= 1) sum += __shfl_xor(sum, off);
        if (lane == 0) rsum[q] = sum;
    }
    __syncthreads();

    // ---- PV: wave w owns row q=w; lane owns 4 v-columns
    {
        const int q = w;
        const int vs = lane;
        float4 acc = {0.f, 0.f, 0.f, 0.f};
        const float* vb = V + (size_t)b * NKV * DD + vs * 4;
        const int vlr = (vl + 3) & ~3;   // <= 1024; P==0 in the pad
        for (int kk = 0; kk < vlr; kk += 4) {
#pragma unroll
            for (int u = 0; u < 4; ++u) {
                float p = sc[q][kk + u];
                float4 vv = *(const float4*)(vb + (size_t)(kk + u) * DD);
                acc.x = fmaf(p, vv.x, acc.x);
                acc.y = fmaf(p, vv.y, acc.y);
                acc.z = fmaf(p, vv.z, acc.z);
                acc.w = fmaf(p, vv.w, acc.w);
            }
        }
        float rinv = 1.0f / rsum[q];
        acc.x *= rinv; acc.y *= rinv; acc.z *= rinv; acc.w *= rinv;
        *(float4*)(out + (size_t)(b * NQ + q0 + q) * DD + vs * 4) = acc;
    }
}

// ---------------------------------------------------------------------------
extern "C" void kernel_launch(void* const* d_in, const int* in_sizes, int n_in,
                              void* d_out, int out_size, void* d_ws, size_t ws_size,
                              hipStream_t stream) {
    const float* Q   = (const float*)d_in[0];
    const float* K   = (const float*)d_in[1];
    const float* V   = (const float*)d_in[2];
    const int*   vls = (const int*)  d_in[3];
    const float* Wq  = (const float*)d_in[4];
    const float* Wk  = (const float*)d_in[5];
    const float* Wv  = (const float*)d_in[6];
    float* out = (float*)d_out;

    // workspace layout: Eq (B*NQ*H f32 = 1 MB) | Ek (B*NKV*H f32 = 4 MB)
    float* eq = (float*)d_ws;
    float* ek = eq + (size_t)BB * NQ * HH;

    proj_exp_kernel<<<(BB*NQ + BB*NKV) / 16, 128, 0, stream>>>(Q, K, Wq, Wk, eq, ek);
    attn_kernel<<<BB * (NQ / 8), 512, 0, stream>>>(V, vls, Wv, eq, ek, out);
}